// Round 8
// baseline (538.496 us; speedup 1.0000x reference)
//
#include <hip/hip_runtime.h>

// ---------------------------------------------------------------------------
// R11: v_cvt_pk_bf16_f32 for paired f32->bf16 conversions (feat oabs/oprd,
//     enc convA, aggregate output). feat's VALU budget was the co-bottleneck
//     (VALUBusy 31% vs MfmaUtil 15.5%): 32 manual 4-op f2bf per thread/step
//     -> 16 single-op cvt_pk. Strided epilogue stores keep scalar f2bf.
// Carried from R10 (529us best): 8-wave layer_mfma (16 waves/CU, 3-buf
// counted vmcnt), BM=128 tiles, R8 enc structure, R3 feat/logits/aggregate
// structure, hierarchical scan CSR, fused epilogues.
// ---------------------------------------------------------------------------

#define NODES 50000
#define EDGES 300000
#define PAIRS 200000
#define SCAN_BLK 49  // ceil(NODES/1024)

typedef __attribute__((ext_vector_type(8))) short short8;
typedef __attribute__((ext_vector_type(4))) float f32x4;

__device__ __forceinline__ unsigned short f2bf(float f) {
  unsigned int u = __float_as_uint(f);
  u += 0x7fff + ((u >> 16) & 1);
  return (unsigned short)(u >> 16);
}
__device__ __forceinline__ float bf2f(unsigned short h) {
  return __uint_as_float(((unsigned int)h) << 16);
}
// packed f32x2 -> bf16x2 (lo -> bits[15:0], hi -> bits[31:16])
__device__ __forceinline__ unsigned int cvt_pk(float lo, float hi) {
  unsigned int r;
  asm("v_cvt_pk_bf16_f32 %0, %1, %2" : "=v"(r) : "v"(lo), "v"(hi));
  return r;
}

__device__ __forceinline__ void glds16(const void* g, void* l) {
  __builtin_amdgcn_global_load_lds(
      (const __attribute__((address_space(1))) unsigned int*)g,
      (__attribute__((address_space(3))) unsigned int*)l, 16, 0, 0);
}

// ---------------- CSR build ----------------

__global__ __launch_bounds__(256) void count_deg_kernel(const int* __restrict__ dst,
                                                        int* __restrict__ cnt) {
  int e = blockIdx.x * 256 + threadIdx.x;
  if (e < EDGES) atomicAdd(&cnt[dst[e]], 1);
}

__global__ __launch_bounds__(256) void blocksum_kernel(const int* __restrict__ cnt,
                                                       int* __restrict__ bsum) {
  int base = blockIdx.x * 1024 + threadIdx.x * 4;
  int s = 0;
  if (base + 3 < NODES) {
    int4 v = *(const int4*)(cnt + base);
    s = v.x + v.y + v.z + v.w;
  } else {
#pragma unroll
    for (int k = 0; k < 4; ++k)
      if (base + k < NODES) s += cnt[base + k];
  }
#pragma unroll
  for (int off = 32; off; off >>= 1) s += __shfl_down(s, off);
  __shared__ int ws[4];
  if ((threadIdx.x & 63) == 0) ws[threadIdx.x >> 6] = s;
  __syncthreads();
  if (threadIdx.x == 0) bsum[blockIdx.x] = ws[0] + ws[1] + ws[2] + ws[3];
}

__global__ __launch_bounds__(64) void scan_bsum_kernel(const int* __restrict__ bsum,
                                                       int* __restrict__ boff) {
  int lane = threadIdx.x;
  int v = (lane < SCAN_BLK) ? bsum[lane] : 0;
  int incl = v;
#pragma unroll
  for (int off = 1; off < 64; off <<= 1) {
    int t = __shfl_up(incl, off);
    if (lane >= off) incl += t;
  }
  if (lane < SCAN_BLK) boff[lane] = incl - v;
}

__global__ __launch_bounds__(256) void scan_final_kernel(const int* __restrict__ cnt,
                                                         const int* __restrict__ boff,
                                                         int* __restrict__ row_start,
                                                         float* __restrict__ degf) {
  int base = blockIdx.x * 1024 + threadIdx.x * 4;
  int c[4] = {0, 0, 0, 0};
  if (base + 3 < NODES) {
    int4 v = *(const int4*)(cnt + base);
    c[0] = v.x; c[1] = v.y; c[2] = v.z; c[3] = v.w;
  } else {
#pragma unroll
    for (int k = 0; k < 4; ++k)
      if (base + k < NODES) c[k] = cnt[base + k];
  }
  int s = c[0] + c[1] + c[2] + c[3];
  int lane = threadIdx.x & 63, wv = threadIdx.x >> 6;
  int incl = s;
#pragma unroll
  for (int off = 1; off < 64; off <<= 1) {
    int t = __shfl_up(incl, off);
    if (lane >= off) incl += t;
  }
  __shared__ int wsum[4];
  if (lane == 63) wsum[wv] = incl;
  __syncthreads();
  int wbase = 0;
  for (int k = 0; k < wv; ++k) wbase += wsum[k];
  int rs = boff[blockIdx.x] + wbase + incl - s;
#pragma unroll
  for (int k = 0; k < 4; ++k) {
    int i = base + k;
    if (i < NODES) {
      row_start[i] = rs;
      degf[i] = (float)(c[k] > 0 ? c[k] : 1);
      rs += c[k];
    }
  }
  if (blockIdx.x == 0 && threadIdx.x == 0) row_start[NODES] = EDGES;
}

__global__ __launch_bounds__(256) void fill_csr_kernel(const int* __restrict__ src,
                                                       const int* __restrict__ dst,
                                                       const int* __restrict__ row_start,
                                                       int* __restrict__ cursor,
                                                       int* __restrict__ csr) {
  int e = blockIdx.x * 256 + threadIdx.x;
  if (e < EDGES) {
    int d = dst[e];
    int pos = atomicAdd(&cursor[d], 1);
    csr[row_start[d] + pos] = src[e];
  }
}

// ---------------- weight transpose+convert ----------------

__global__ __launch_bounds__(256) void tconv_kernel(const float* __restrict__ in,
                                                    unsigned short* __restrict__ out,
                                                    int R, int C) {
  const float* inb = in + (size_t)blockIdx.z * R * C;
  unsigned short* outb = out + (size_t)blockIdx.z * R * C;
  __shared__ float t[32][33];
  int bx = blockIdx.x * 32, by = blockIdx.y * 32;
  int tx = threadIdx.x & 31, ty = threadIdx.x >> 5;
#pragma unroll
  for (int i = ty; i < 32; i += 8) t[i][tx] = inb[(size_t)(by + i) * C + bx + tx];
  __syncthreads();
#pragma unroll
  for (int i = ty; i < 32; i += 8)
    outb[(size_t)(bx + i) * R + by + tx] = f2bf(t[tx][i]);
}

// ---------------- encoder GEMM: BM=128, F32A, depth-1 dbuf -----------------
__global__ __launch_bounds__(256, 2) void enc_mfma(
    const float* __restrict__ Af, const unsigned short* __restrict__ Bt,
    const float* __restrict__ bias1, unsigned short* __restrict__ Cb,
    int M, int K) {
  __shared__ __attribute__((aligned(16))) unsigned short sm[2][384 * 32];  // 48KB
  const int tid = threadIdx.x;
  const int wv = tid >> 6, ln = tid & 63;
  const int lane15 = ln & 15, quad = ln >> 4;
  const int bm = blockIdx.x * 128;
  f32x4 acc[8][4] = {};
  const int NS = K >> 5;

  auto stage_B = [&](int buf, int k0) {
#pragma unroll
    for (int q = 2; q < 6; ++q) {
      int L = q * 256 + tid;
      int rr = L >> 2, ck = (L & 3) * 8;
      glds16(Bt + (size_t)(rr - 128) * K + k0 + ck,
             sm[buf] + (size_t)(q * 256 + (tid & 192)) * 8);
    }
  };
  auto compute_tile = [&](const unsigned short* smc) {
    const unsigned short* Bsm = smc + 128 * 32;
    short8 af[8], bfr[4];
#pragma unroll
    for (int t = 0; t < 8; ++t)
      af[t] = *(const short8*)&smc[(t * 16 + lane15) * 32 + quad * 8];
#pragma unroll
    for (int t = 0; t < 4; ++t)
      bfr[t] = *(const short8*)&Bsm[(wv * 64 + t * 16 + lane15) * 32 + quad * 8];
#pragma unroll
    for (int mt = 0; mt < 8; ++mt)
#pragma unroll
      for (int nt = 0; nt < 4; ++nt)
        acc[mt][nt] = __builtin_amdgcn_mfma_f32_16x16x32_bf16(af[mt], bfr[nt],
                                                              acc[mt][nt], 0, 0, 0);
  };

  const int ar_ = tid >> 1, aks = (tid & 1) * 16;
  int agr = bm + ar_;
  if (agr > M - 1) agr = M - 1;
  const float* aRow = Af + (size_t)agr * K;

  auto convA = [&](int buf, float4 f0, float4 f1, float4 f2, float4 f3) {
    __attribute__((aligned(16))) unsigned int o[8];
    o[0] = cvt_pk(f0.x, f0.y); o[1] = cvt_pk(f0.z, f0.w);
    o[2] = cvt_pk(f1.x, f1.y); o[3] = cvt_pk(f1.z, f1.w);
    o[4] = cvt_pk(f2.x, f2.y); o[5] = cvt_pk(f2.z, f2.w);
    o[6] = cvt_pk(f3.x, f3.y); o[7] = cvt_pk(f3.z, f3.w);
    *(uint4*)&sm[buf][ar_ * 32 + aks] = *(uint4*)&o[0];
    *(uint4*)&sm[buf][ar_ * 32 + aks + 8] = *(uint4*)&o[4];
  };

  {
    const float* p = aRow + aks;
    float4 f0 = *(const float4*)(p), f1 = *(const float4*)(p + 4);
    float4 f2 = *(const float4*)(p + 8), f3 = *(const float4*)(p + 12);
    stage_B(0, 0);
    convA(0, f0, f1, f2, f3);
  }
  __syncthreads();

  int cur = 0;
  for (int s = 0; s < NS; ++s) {
    const int nb = cur ^ 1;
    const bool has_next = (s + 1 < NS);
    float4 nf0, nf1, nf2, nf3;
    if (has_next) {
      const float* p = aRow + (s + 1) * 32 + aks;
      nf0 = *(const float4*)(p);
      nf1 = *(const float4*)(p + 4);
      nf2 = *(const float4*)(p + 8);
      nf3 = *(const float4*)(p + 12);
      stage_B(nb, (s + 1) * 32);
    }
    compute_tile(sm[cur]);
    if (has_next) convA(nb, nf0, nf1, nf2, nf3);
    __syncthreads();
    cur = nb;
  }

  float bsum[4];
#pragma unroll
  for (int nt = 0; nt < 4; ++nt) bsum[nt] = bias1[wv * 64 + nt * 16 + lane15];
#pragma unroll
  for (int mt = 0; mt < 8; ++mt)
#pragma unroll
    for (int r = 0; r < 4; ++r) {
      int row = bm + mt * 16 + quad * 4 + r;
      if (row < M) {
#pragma unroll
        for (int nt = 0; nt < 4; ++nt)
          Cb[(size_t)row * 256 + wv * 64 + nt * 16 + lane15] =
              f2bf(fmaxf(acc[mt][nt][r] + bsum[nt], 0.f));
      }
    }
}

// ---------------- layer GEMM: BM=128, 8-wave blocks, 3-buf counted vmcnt ---
// (R10, unchanged — 16 waves/CU won)
template <int EPI>
__global__ __launch_bounds__(512, 4) void layer_mfma(
    const unsigned short* __restrict__ A, const unsigned short* __restrict__ Bt,
    const unsigned short* __restrict__ A2, const unsigned short* __restrict__ B2t,
    const float* __restrict__ bias1, const float* __restrict__ bias2,
    const float* __restrict__ gamma, const float* __restrict__ beta,
    unsigned short* __restrict__ Cb, float* __restrict__ Cf, int M) {
  __shared__ __attribute__((aligned(16))) unsigned short sm[3][384 * 32];  // 72KB
  __shared__ float red1[4][128], red2[4][128];
  __shared__ float mu_s[128], rs_s[128];
  const int tid = threadIdx.x;
  const int wv = tid >> 6, ln = tid & 63;
  const int lane15 = ln & 15, quad = ln >> 4;
  const int wr = wv >> 2, wc = wv & 3;  // 2M x 4N wave grid
  const int bm = blockIdx.x * 128;
  f32x4 acc[4][4] = {};

  auto stage = [&](int buf, int s) {
    const unsigned short* __restrict__ Ap = (s < 8) ? A : A2;
    const unsigned short* __restrict__ Bp = (s < 8) ? Bt : B2t;
    const int k0 = (s & 7) * 32;
#pragma unroll
    for (int q = 0; q < 3; ++q) {
      int L = q * 512 + tid;
      int r = L >> 2, ck = (L & 3) * 8;
      const unsigned short* gp;
      if (r < 128) {
        int gr = bm + r;
        if (gr > M - 1) gr = M - 1;
        gp = Ap + (size_t)gr * 256 + k0 + ck;
      } else {
        gp = Bp + (size_t)(r - 128) * 256 + k0 + ck;
      }
      glds16(gp, sm[buf] + (size_t)(q * 512 + (tid & 448)) * 8);
    }
  };
  auto compute_tile = [&](const unsigned short* smc) {
    const unsigned short* Bsm = smc + 128 * 32;
    short8 af[4], bfr[4];
#pragma unroll
    for (int t = 0; t < 4; ++t) {
      af[t] = *(const short8*)&smc[(wr * 64 + t * 16 + lane15) * 32 + quad * 8];
      bfr[t] = *(const short8*)&Bsm[(wc * 64 + t * 16 + lane15) * 32 + quad * 8];
    }
#pragma unroll
    for (int mt = 0; mt < 4; ++mt)
#pragma unroll
      for (int nt = 0; nt < 4; ++nt)
        acc[mt][nt] = __builtin_amdgcn_mfma_f32_16x16x32_bf16(af[mt], bfr[nt],
                                                              acc[mt][nt], 0, 0, 0);
  };

  stage(0, 0);
  stage(1, 1);
  for (int s = 0; s < 16; ++s) {
    if (s < 15) {
      asm volatile("s_waitcnt vmcnt(3)" ::: "memory");  // next tile stays in flight
    } else {
      asm volatile("s_waitcnt vmcnt(0)" ::: "memory");
    }
    __builtin_amdgcn_sched_barrier(0);
    __builtin_amdgcn_s_barrier();
    __builtin_amdgcn_sched_barrier(0);
    if (s + 2 < 16) stage((s + 2) % 3, s + 2);  // overwrites buffer of compute(s-1)
    compute_tile(sm[s % 3]);
  }
  __builtin_amdgcn_sched_barrier(0);

  // ---- epilogue (in-place on acc): relu -> LN (-> L2norm) ----
  float bsum[4], gg[4], bb[4];
#pragma unroll
  for (int nt = 0; nt < 4; ++nt) {
    int col = wc * 64 + nt * 16 + lane15;
    bsum[nt] = bias1[col] + bias2[col];
    gg[nt] = gamma[col];
    bb[nt] = beta[col];
  }
#pragma unroll
  for (int mt = 0; mt < 4; ++mt)
#pragma unroll
    for (int nt = 0; nt < 4; ++nt)
#pragma unroll
      for (int r = 0; r < 4; ++r)
        acc[mt][nt][r] = fmaxf(acc[mt][nt][r] + bsum[nt], 0.f);

  float s1[4][4], s2[4][4];
#pragma unroll
  for (int mt = 0; mt < 4; ++mt)
#pragma unroll
    for (int r = 0; r < 4; ++r) {
      float a = 0.f, b = 0.f;
#pragma unroll
      for (int nt = 0; nt < 4; ++nt) {
        a += acc[mt][nt][r];
        b += acc[mt][nt][r] * acc[mt][nt][r];
      }
      s1[mt][r] = a;
      s2[mt][r] = b;
    }
#pragma unroll
  for (int st = 1; st < 16; st <<= 1)
#pragma unroll
    for (int mt = 0; mt < 4; ++mt)
#pragma unroll
      for (int r = 0; r < 4; ++r) {
        s1[mt][r] += __shfl_xor(s1[mt][r], st, 64);
        s2[mt][r] += __shfl_xor(s2[mt][r], st, 64);
      }
  if (lane15 == 0) {
#pragma unroll
    for (int mt = 0; mt < 4; ++mt)
#pragma unroll
      for (int r = 0; r < 4; ++r) {
        int rowl = wr * 64 + mt * 16 + quad * 4 + r;
        red1[wc][rowl] = s1[mt][r];
        red2[wc][rowl] = s2[mt][r];
      }
  }
  __syncthreads();
  if (tid < 128) {
    float a = red1[0][tid] + red1[1][tid] + red1[2][tid] + red1[3][tid];
    float b = red2[0][tid] + red2[1][tid] + red2[2][tid] + red2[3][tid];
    float mu = a * (1.f / 256.f);
    float var = fmaxf(b * (1.f / 256.f) - mu * mu, 0.f);
    mu_s[tid] = mu;
    rs_s[tid] = rsqrtf(var + 1e-5f);
  }
  __syncthreads();
#pragma unroll
  for (int mt = 0; mt < 4; ++mt)
#pragma unroll
    for (int r = 0; r < 4; ++r) {
      int rowl = wr * 64 + mt * 16 + quad * 4 + r;
      float mu = mu_s[rowl], rstd = rs_s[rowl];
#pragma unroll
      for (int nt = 0; nt < 4; ++nt)
        acc[mt][nt][r] = (acc[mt][nt][r] - mu) * rstd * gg[nt] + bb[nt];
    }

  if (EPI == 1) {
#pragma unroll
    for (int mt = 0; mt < 4; ++mt)
#pragma unroll
      for (int r = 0; r < 4; ++r) {
        int row = bm + wr * 64 + mt * 16 + quad * 4 + r;
        if (row < M) {
#pragma unroll
          for (int nt = 0; nt < 4; ++nt)
            Cb[(size_t)row * 256 + wc * 64 + nt * 16 + lane15] =
                f2bf(acc[mt][nt][r]);
        }
      }
    return;
  }

  // EPI==2: L2 normalize; store f32 Cf and bf16 Cb
  __syncthreads();
#pragma unroll
  for (int mt = 0; mt < 4; ++mt)
#pragma unroll
    for (int r = 0; r < 4; ++r) {
      float b = 0.f;
#pragma unroll
      for (int nt = 0; nt < 4; ++nt) b += acc[mt][nt][r] * acc[mt][nt][r];
      s2[mt][r] = b;
    }
#pragma unroll
  for (int st = 1; st < 16; st <<= 1)
#pragma unroll
    for (int mt = 0; mt < 4; ++mt)
#pragma unroll
      for (int r = 0; r < 4; ++r) s2[mt][r] += __shfl_xor(s2[mt][r], st, 64);
  if (lane15 == 0) {
#pragma unroll
    for (int mt = 0; mt < 4; ++mt)
#pragma unroll
      for (int r = 0; r < 4; ++r)
        red1[wc][wr * 64 + mt * 16 + quad * 4 + r] = s2[mt][r];
  }
  __syncthreads();
  if (tid < 128) {
    float b = red1[0][tid] + red1[1][tid] + red1[2][tid] + red1[3][tid];
    mu_s[tid] = 1.f / fmaxf(sqrtf(b), 1e-12f);
  }
  __syncthreads();
#pragma unroll
  for (int mt = 0; mt < 4; ++mt)
#pragma unroll
    for (int r = 0; r < 4; ++r) {
      int rowl = wr * 64 + mt * 16 + quad * 4 + r;
      int row = bm + rowl;
      float inv = mu_s[rowl];
      if (row < M) {
#pragma unroll
        for (int nt = 0; nt < 4; ++nt) {
          float y = acc[mt][nt][r] * inv;
          size_t idx = (size_t)row * 256 + wc * 64 + nt * 16 + lane15;
          Cf[idx] = y;
          Cb[idx] = f2bf(y);
        }
      }
    }
}

// ---------------- feat GEMM: single-read dual A-tile, cvt_pk converts ------
__global__ __launch_bounds__(256) void feat_mfma_kernel(
    const unsigned short* __restrict__ Hb, const int* __restrict__ i_idx,
    const int* __restrict__ j_idx, const unsigned short* __restrict__ W1t,
    const float* __restrict__ b1, unsigned short* __restrict__ z1) {
  __shared__ __attribute__((aligned(16))) unsigned short Aabs[128 * 32];
  __shared__ __attribute__((aligned(16))) unsigned short Aprd[128 * 32];
  __shared__ __attribute__((aligned(16))) unsigned short Blo[128 * 32];
  __shared__ __attribute__((aligned(16))) unsigned short Bhi[128 * 32];
  __shared__ int ii[128], jj[128];
  const int tid = threadIdx.x;
  const int wv = tid >> 6, ln = tid & 63;
  const int lane15 = ln & 15, quad = ln >> 4;
  const int mhalf = wv >> 1, nhalf = wv & 1;
  const int bm = blockIdx.x * 128;
  if (tid < 128) {
    int p = bm + tid;
    if (p > PAIRS - 1) p = PAIRS - 1;
    ii[tid] = i_idx[p];
    jj[tid] = j_idx[p];
  }
  f32x4 acc[4][4] = {};
  const int ar = tid >> 1;
  const int ak = (tid & 1) * 16;

  for (int k0 = 0; k0 < 256; k0 += 32) {
    __syncthreads();
#pragma unroll
    for (int q = 0; q < 2; ++q) {
      int L = q * 256 + tid;
      int r = L >> 2, ck = (L & 3) * 8;
      glds16(W1t + (size_t)r * 512 + k0 + ck,
             Blo + (size_t)(q * 256 + (tid & 192)) * 8);
      glds16(W1t + (size_t)r * 512 + 256 + k0 + ck,
             Bhi + (size_t)(q * 256 + (tid & 192)) * 8);
    }
    {
      int kk = k0 + ak;
      const unsigned short* hi = Hb + (size_t)ii[ar] * 256 + kk;
      const unsigned short* hj = Hb + (size_t)jj[ar] * 256 + kk;
      union U { uint4 v; unsigned short s[8]; };
      U a0, a1, c0, c1;
      a0.v = *(const uint4*)(hi);
      a1.v = *(const uint4*)(hi + 8);
      c0.v = *(const uint4*)(hj);
      c1.v = *(const uint4*)(hj + 8);
      __attribute__((aligned(16))) unsigned int oabs[8], oprd[8];
#pragma unroll
      for (int e = 0; e < 8; e += 2) {
        float x0 = bf2f(a0.s[e]), y0 = bf2f(c0.s[e]);
        float x1 = bf2f(a0.s[e + 1]), y1 = bf2f(c0.s[e + 1]);
        oabs[e >> 1] = cvt_pk(fabsf(x0 - y0), fabsf(x1 - y1));
        oprd[e >> 1] = cvt_pk(x0 * y0, x1 * y1);
      }
#pragma unroll
      for (int e = 0; e < 8; e += 2) {
        float x0 = bf2f(a1.s[e]), y0 = bf2f(c1.s[e]);
        float x1 = bf2f(a1.s[e + 1]), y1 = bf2f(c1.s[e + 1]);
        oabs[4 + (e >> 1)] = cvt_pk(fabsf(x0 - y0), fabsf(x1 - y1));
        oprd[4 + (e >> 1)] = cvt_pk(x0 * y0, x1 * y1);
      }
      *(uint4*)&Aabs[ar * 32 + ak] = *(uint4*)&oabs[0];
      *(uint4*)&Aabs[ar * 32 + ak + 8] = *(uint4*)&oabs[4];
      *(uint4*)&Aprd[ar * 32 + ak] = *(uint4*)&oprd[0];
      *(uint4*)&Aprd[ar * 32 + ak + 8] = *(uint4*)&oprd[4];
    }
    __syncthreads();
    short8 aA[4], aP[4], bL[4], bH[4];
#pragma unroll
    for (int t = 0; t < 4; ++t) {
      int arow = (mhalf * 64 + t * 16 + lane15) * 32 + quad * 8;
      int brow = (nhalf * 64 + t * 16 + lane15) * 32 + quad * 8;
      aA[t] = *(const short8*)&Aabs[arow];
      aP[t] = *(const short8*)&Aprd[arow];
      bL[t] = *(const short8*)&Blo[brow];
      bH[t] = *(const short8*)&Bhi[brow];
    }
#pragma unroll
    for (int mt = 0; mt < 4; ++mt)
#pragma unroll
      for (int nt = 0; nt < 4; ++nt) {
        acc[mt][nt] = __builtin_amdgcn_mfma_f32_16x16x32_bf16(aA[mt], bL[nt],
                                                              acc[mt][nt], 0, 0, 0);
        acc[mt][nt] = __builtin_amdgcn_mfma_f32_16x16x32_bf16(aP[mt], bH[nt],
                                                              acc[mt][nt], 0, 0, 0);
      }
  }

  float bsum[4];
#pragma unroll
  for (int nt = 0; nt < 4; ++nt) bsum[nt] = b1[nhalf * 64 + nt * 16 + lane15];
#pragma unroll
  for (int mt = 0; mt < 4; ++mt) {
    int rb = bm + mhalf * 64 + mt * 16 + quad * 4;
#pragma unroll
    for (int r = 0; r < 4; ++r) {
      int p = rb + r;
      if (p < PAIRS) {
#pragma unroll
        for (int nt = 0; nt < 4; ++nt) {
          float v = fmaxf(acc[mt][nt][r] + bsum[nt], 0.f);
          z1[(size_t)p * 128 + nhalf * 64 + nt * 16 + lane15] = f2bf(v);
        }
      }
    }
  }
}

// ---------------- z2 GEMM with fused logits, double-buffered ---------------
__global__ __launch_bounds__(256) void gemm_logits_kernel(
    const unsigned short* __restrict__ z1, const unsigned short* __restrict__ W2t,
    const float* __restrict__ b2, const float* __restrict__ W3,
    const float* __restrict__ b3, float* __restrict__ out) {
  __shared__ __attribute__((aligned(16))) unsigned short As[2][128 * 32];
  __shared__ __attribute__((aligned(16))) unsigned short Bs[2][128 * 32];
  __shared__ float red[2][128];
  const int tid = threadIdx.x;
  const int wv = tid >> 6, ln = tid & 63;
  const int lane15 = ln & 15, quad = ln >> 4;
  const int mhalf = wv >> 1, nhalf = wv & 1;
  const int bm = blockIdx.x * 128;
  f32x4 acc[4][4] = {};

  auto stageL = [&](int buf, int k0) {
#pragma unroll
    for (int q = 0; q < 2; ++q) {
      int L = (q * 4 + wv) * 64 + ln;
      int r = L >> 2, ck = (L & 3) * 8;
      int gr = bm + r;
      if (gr > PAIRS - 1) gr = PAIRS - 1;
      glds16(z1 + (size_t)gr * 128 + k0 + ck, As[buf] + (size_t)(q * 4 + wv) * 512);
      glds16(W2t + (size_t)r * 128 + k0 + ck, Bs[buf] + (size_t)(q * 4 + wv) * 512);
    }
  };

  stageL(0, 0);
  __syncthreads();

  int cur = 0;
  for (int s = 0; s < 4; ++s) {
    const int nb = cur ^ 1;
    if (s < 3) stageL(nb, (s + 1) * 32);
    short8 af[4], bfr[4];
#pragma unroll
    for (int t = 0; t < 4; ++t) {
      af[t] = *(const short8*)&As[cur][(mhalf * 64 + t * 16 + lane15) * 32 + quad * 8];
      bfr[t] = *(const short8*)&Bs[cur][(nhalf * 64 + t * 16 + lane15) * 32 + quad * 8];
    }
#pragma unroll
    for (int mt = 0; mt < 4; ++mt)
#pragma unroll
      for (int nt = 0; nt < 4; ++nt)
        acc[mt][nt] = __builtin_amdgcn_mfma_f32_16x16x32_bf16(af[mt], bfr[nt],
                                                              acc[mt][nt], 0, 0, 0);
    __syncthreads();
    cur = nb;
  }

  float bsum[4], w3v[4];
#pragma unroll
  for (int nt = 0; nt < 4; ++nt) {
    int col = nhalf * 64 + nt * 16 + lane15;
    bsum[nt] = b2[col];
    w3v[nt] = W3[col];
  }
  float p[4][4];
#pragma unroll
  for (int mt = 0; mt < 4; ++mt)
#pragma unroll
    for (int r = 0; r < 4; ++r) {
      float s = 0.f;
#pragma unroll
      for (int nt = 0; nt < 4; ++nt)
        s += fmaxf(acc[mt][nt][r] + bsum[nt], 0.f) * w3v[nt];
      p[mt][r] = s;
    }
#pragma unroll
  for (int st = 1; st < 16; st <<= 1)
#pragma unroll
    for (int mt = 0; mt < 4; ++mt)
#pragma unroll
      for (int r = 0; r < 4; ++r) p[mt][r] += __shfl_xor(p[mt][r], st, 64);
  if (lane15 == 0) {
#pragma unroll
    for (int mt = 0; mt < 4; ++mt)
#pragma unroll
      for (int r = 0; r < 4; ++r)
        red[nhalf][mhalf * 64 + mt * 16 + quad * 4 + r] = p[mt][r];
  }
  __syncthreads();
  if (tid < 128) {
    int prow = bm + tid;
    if (prow < PAIRS) out[prow] = red[0][tid] + red[1][tid] + b3[0];
  }
}

// ---------------- graph aggregate ----------------

__global__ __launch_bounds__(256) void aggregate_kernel(
    const unsigned short* __restrict__ h, const int* __restrict__ row_start,
    const int* __restrict__ csr, const float* __restrict__ degf,
    unsigned short* __restrict__ mean) {
  int wid = threadIdx.x >> 6, lane = threadIdx.x & 63;
  int n = blockIdx.x * 4 + wid;
  if (n >= NODES) return;
  int rs = row_start[n], re = row_start[n + 1];
  float a0 = 0.f, a1 = 0.f, a2 = 0.f, a3 = 0.f;
  int e = rs;
  for (; e + 2 <= re; e += 2) {
    int s0 = csr[e], s1 = csr[e + 1];
    ushort4 v0 = *(const ushort4*)(h + (size_t)s0 * 256 + lane * 4);
    ushort4 v1 = *(const ushort4*)(h + (size_t)s1 * 256 + lane * 4);
    a0 += bf2f(v0.x) + bf2f(v1.x);
    a1 += bf2f(v0.y) + bf2f(v1.y);
    a2 += bf2f(v0.z) + bf2f(v1.z);
    a3 += bf2f(v0.w) + bf2f(v1.w);
  }
  if (e < re) {
    ushort4 v0 = *(const ushort4*)(h + (size_t)csr[e] * 256 + lane * 4);
    a0 += bf2f(v0.x); a1 += bf2f(v0.y); a2 += bf2f(v0.z); a3 += bf2f(v0.w);
  }
  float inv = 1.0f / degf[n];
  uint2 o;
  o.x = cvt_pk(a0 * inv, a1 * inv);
  o.y = cvt_pk(a2 * inv, a3 * inv);
  *(uint2*)(mean + (size_t)n * 256 + lane * 4) = o;
}

// ---------------- host ----------------

extern "C" void kernel_launch(void* const* d_in, const int* in_sizes, int n_in,
                              void* d_out, int out_size, void* d_ws, size_t ws_size,
                              hipStream_t stream) {
  const float* X       = (const float*)d_in[0];
  const int*   edge    = (const int*)d_in[1];
  const int*   i_idx   = (const int*)d_in[2];
  const int*   j_idx   = (const int*)d_in[3];
  const float* W_in    = (const float*)d_in[4];
  const float* b_in    = (const float*)d_in[5];
  const float* Ws_self = (const float*)d_in[6];
  const float* bs_self = (const float*)d_in[7];
  const float* Ws_nei  = (const float*)d_in[8];
  const float* bs_nei  = (const float*)d_in[9];
  const float* gammas  = (const float*)d_in[10];
  const float* betas   = (const float*)d_in[11];
  const float* W1      = (const float*)d_in[12];
  const float* b1      = (const float*)d_in[13];
  const float* W2      = (const float*)d_in[14];
  const float* b2      = (const float*)d_in[15];
  const float* W3      = (const float*)d_in[16];
  const float* b3      = (const float*)d_in[17];

  char* w = (char*)d_ws;
  size_t off = 0;
  auto alloc = [&](size_t bytes) {
    char* p = w + off;
    off += (bytes + 255) & ~(size_t)255;
    return p;
  };
  unsigned short* hA   = (unsigned short*)alloc((size_t)NODES * 256 * 2);  // 25.6MB
  unsigned short* hB   = (unsigned short*)alloc((size_t)NODES * 256 * 2);
  unsigned short* mean = (unsigned short*)alloc((size_t)NODES * 256 * 2);
  unsigned short* Hb   = (unsigned short*)alloc((size_t)NODES * 256 * 2);
  float* degf     = (float*)alloc((size_t)NODES * 4);
  int* cnt        = (int*)alloc((size_t)2 * NODES * 4);
  int* cursor     = cnt + NODES;
  int* row_start  = (int*)alloc((size_t)(NODES + 1) * 4);
  int* csr        = (int*)alloc((size_t)EDGES * 4);
  int* bsum       = (int*)alloc((size_t)(SCAN_BLK + 1) * 4);
  int* boff       = (int*)alloc((size_t)(SCAN_BLK + 1) * 4);
  unsigned short* WinT   = (unsigned short*)alloc((size_t)480 * 256 * 2);
  unsigned short* WselfT = (unsigned short*)alloc((size_t)3 * 256 * 256 * 2);
  unsigned short* WneiT  = (unsigned short*)alloc((size_t)3 * 256 * 256 * 2);
  unsigned short* W1T    = (unsigned short*)alloc((size_t)512 * 128 * 2);
  unsigned short* W2T    = (unsigned short*)alloc((size_t)128 * 128 * 2);
  unsigned short* z1 = hA;  // reuse (hA/hB dead after layer 3)

  const int* src = edge;
  const int* dst = edge + EDGES;
  float* Hout   = (float*)d_out;
  float* logits = (float*)d_out + (size_t)NODES * 256;

  // weight conversions
  tconv_kernel<<<dim3(8, 15, 1), 256, 0, stream>>>(W_in, WinT, 480, 256);
  tconv_kernel<<<dim3(8, 8, 3), 256, 0, stream>>>(Ws_self, WselfT, 256, 256);
  tconv_kernel<<<dim3(8, 8, 3), 256, 0, stream>>>(Ws_nei, WneiT, 256, 256);
  tconv_kernel<<<dim3(4, 16, 1), 256, 0, stream>>>(W1, W1T, 512, 128);
  tconv_kernel<<<dim3(4, 4, 1), 256, 0, stream>>>(W2, W2T, 128, 128);

  // CSR build (hierarchical scan)
  hipMemsetAsync(cnt, 0, (size_t)2 * NODES * 4, stream);
  count_deg_kernel<<<(EDGES + 255) / 256, 256, 0, stream>>>(dst, cnt);
  blocksum_kernel<<<SCAN_BLK, 256, 0, stream>>>(cnt, bsum);
  scan_bsum_kernel<<<1, 64, 0, stream>>>(bsum, boff);
  scan_final_kernel<<<SCAN_BLK, 256, 0, stream>>>(cnt, boff, row_start, degf);
  fill_csr_kernel<<<(EDGES + 255) / 256, 256, 0, stream>>>(src, dst, row_start, cursor, csr);

  // encoder: hA = relu(X @ W_in + b_in), fp32 A staged in-kernel, BM=128
  enc_mfma<<<391, 256, 0, stream>>>(X, WinT, b_in, hA, NODES, 480);

  unsigned short* hcur = hA;
  unsigned short* hnext = hB;
  for (int l = 0; l < 3; ++l) {
    aggregate_kernel<<<NODES / 4, 256, 0, stream>>>(hcur, row_start, csr, degf, mean);
    if (l < 2) {
      layer_mfma<1><<<391, 512, 0, stream>>>(
          hcur, WselfT + (size_t)l * 65536, mean, WneiT + (size_t)l * 65536,
          bs_self + l * 256, bs_nei + l * 256, gammas + l * 256, betas + l * 256,
          hnext, nullptr, NODES);
      unsigned short* t = hcur; hcur = hnext; hnext = t;
    } else {
      layer_mfma<2><<<391, 512, 0, stream>>>(
          hcur, WselfT + (size_t)l * 65536, mean, WneiT + (size_t)l * 65536,
          bs_self + l * 256, bs_nei + l * 256, gammas + l * 256, betas + l * 256,
          Hb, Hout, NODES);
    }
  }

  // edge head
  feat_mfma_kernel<<<(PAIRS + 127) / 128, 256, 0, stream>>>(Hb, i_idx, j_idx, W1T, b1, z1);
  gemm_logits_kernel<<<(PAIRS + 127) / 128, 256, 0, stream>>>(z1, W2T, b2, W3, b3, logits);
}

// Round 9
// 528.075 us; speedup vs baseline: 1.0197x; 1.0197x over previous
//
#include <hip/hip_runtime.h>

// ---------------------------------------------------------------------------
// R12: attribution-driven split of R11. feat's inline-asm cvt_pk REVERTED
//     (VGPR 80->100, occupancy 23.6->18.2%, 65->84.5us — m240's warning was
//     right: "v"-constrained asm pins temporaries + fences the scheduler in
//     the gather-convert hot path). enc/aggregate KEEP cvt_pk (total moved
//     +9 vs feat's +19 => those sites netted ~-10us; they have VGPR slack).
// Carried from R10 (529us best): 8-wave layer_mfma (16 waves/CU, 3-buf
// counted vmcnt), BM=128 tiles, R3-structure feat/logits, hierarchical scan
// CSR, fused LN/L2norm/logits epilogues.
// ---------------------------------------------------------------------------

#define NODES 50000
#define EDGES 300000
#define PAIRS 200000
#define SCAN_BLK 49  // ceil(NODES/1024)

typedef __attribute__((ext_vector_type(8))) short short8;
typedef __attribute__((ext_vector_type(4))) float f32x4;

__device__ __forceinline__ unsigned short f2bf(float f) {
  unsigned int u = __float_as_uint(f);
  u += 0x7fff + ((u >> 16) & 1);
  return (unsigned short)(u >> 16);
}
__device__ __forceinline__ float bf2f(unsigned short h) {
  return __uint_as_float(((unsigned int)h) << 16);
}
// packed f32x2 -> bf16x2 (lo -> bits[15:0], hi -> bits[31:16])
__device__ __forceinline__ unsigned int cvt_pk(float lo, float hi) {
  unsigned int r;
  asm("v_cvt_pk_bf16_f32 %0, %1, %2" : "=v"(r) : "v"(lo), "v"(hi));
  return r;
}

__device__ __forceinline__ void glds16(const void* g, void* l) {
  __builtin_amdgcn_global_load_lds(
      (const __attribute__((address_space(1))) unsigned int*)g,
      (__attribute__((address_space(3))) unsigned int*)l, 16, 0, 0);
}

// ---------------- CSR build ----------------

__global__ __launch_bounds__(256) void count_deg_kernel(const int* __restrict__ dst,
                                                        int* __restrict__ cnt) {
  int e = blockIdx.x * 256 + threadIdx.x;
  if (e < EDGES) atomicAdd(&cnt[dst[e]], 1);
}

__global__ __launch_bounds__(256) void blocksum_kernel(const int* __restrict__ cnt,
                                                       int* __restrict__ bsum) {
  int base = blockIdx.x * 1024 + threadIdx.x * 4;
  int s = 0;
  if (base + 3 < NODES) {
    int4 v = *(const int4*)(cnt + base);
    s = v.x + v.y + v.z + v.w;
  } else {
#pragma unroll
    for (int k = 0; k < 4; ++k)
      if (base + k < NODES) s += cnt[base + k];
  }
#pragma unroll
  for (int off = 32; off; off >>= 1) s += __shfl_down(s, off);
  __shared__ int ws[4];
  if ((threadIdx.x & 63) == 0) ws[threadIdx.x >> 6] = s;
  __syncthreads();
  if (threadIdx.x == 0) bsum[blockIdx.x] = ws[0] + ws[1] + ws[2] + ws[3];
}

__global__ __launch_bounds__(64) void scan_bsum_kernel(const int* __restrict__ bsum,
                                                       int* __restrict__ boff) {
  int lane = threadIdx.x;
  int v = (lane < SCAN_BLK) ? bsum[lane] : 0;
  int incl = v;
#pragma unroll
  for (int off = 1; off < 64; off <<= 1) {
    int t = __shfl_up(incl, off);
    if (lane >= off) incl += t;
  }
  if (lane < SCAN_BLK) boff[lane] = incl - v;
}

__global__ __launch_bounds__(256) void scan_final_kernel(const int* __restrict__ cnt,
                                                         const int* __restrict__ boff,
                                                         int* __restrict__ row_start,
                                                         float* __restrict__ degf) {
  int base = blockIdx.x * 1024 + threadIdx.x * 4;
  int c[4] = {0, 0, 0, 0};
  if (base + 3 < NODES) {
    int4 v = *(const int4*)(cnt + base);
    c[0] = v.x; c[1] = v.y; c[2] = v.z; c[3] = v.w;
  } else {
#pragma unroll
    for (int k = 0; k < 4; ++k)
      if (base + k < NODES) c[k] = cnt[base + k];
  }
  int s = c[0] + c[1] + c[2] + c[3];
  int lane = threadIdx.x & 63, wv = threadIdx.x >> 6;
  int incl = s;
#pragma unroll
  for (int off = 1; off < 64; off <<= 1) {
    int t = __shfl_up(incl, off);
    if (lane >= off) incl += t;
  }
  __shared__ int wsum[4];
  if (lane == 63) wsum[wv] = incl;
  __syncthreads();
  int wbase = 0;
  for (int k = 0; k < wv; ++k) wbase += wsum[k];
  int rs = boff[blockIdx.x] + wbase + incl - s;
#pragma unroll
  for (int k = 0; k < 4; ++k) {
    int i = base + k;
    if (i < NODES) {
      row_start[i] = rs;
      degf[i] = (float)(c[k] > 0 ? c[k] : 1);
      rs += c[k];
    }
  }
  if (blockIdx.x == 0 && threadIdx.x == 0) row_start[NODES] = EDGES;
}

__global__ __launch_bounds__(256) void fill_csr_kernel(const int* __restrict__ src,
                                                       const int* __restrict__ dst,
                                                       const int* __restrict__ row_start,
                                                       int* __restrict__ cursor,
                                                       int* __restrict__ csr) {
  int e = blockIdx.x * 256 + threadIdx.x;
  if (e < EDGES) {
    int d = dst[e];
    int pos = atomicAdd(&cursor[d], 1);
    csr[row_start[d] + pos] = src[e];
  }
}

// ---------------- weight transpose+convert ----------------

__global__ __launch_bounds__(256) void tconv_kernel(const float* __restrict__ in,
                                                    unsigned short* __restrict__ out,
                                                    int R, int C) {
  const float* inb = in + (size_t)blockIdx.z * R * C;
  unsigned short* outb = out + (size_t)blockIdx.z * R * C;
  __shared__ float t[32][33];
  int bx = blockIdx.x * 32, by = blockIdx.y * 32;
  int tx = threadIdx.x & 31, ty = threadIdx.x >> 5;
#pragma unroll
  for (int i = ty; i < 32; i += 8) t[i][tx] = inb[(size_t)(by + i) * C + bx + tx];
  __syncthreads();
#pragma unroll
  for (int i = ty; i < 32; i += 8)
    outb[(size_t)(bx + i) * R + by + tx] = f2bf(t[tx][i]);
}

// ---------------- encoder GEMM: BM=128, F32A, depth-1 dbuf -----------------
__global__ __launch_bounds__(256, 2) void enc_mfma(
    const float* __restrict__ Af, const unsigned short* __restrict__ Bt,
    const float* __restrict__ bias1, unsigned short* __restrict__ Cb,
    int M, int K) {
  __shared__ __attribute__((aligned(16))) unsigned short sm[2][384 * 32];  // 48KB
  const int tid = threadIdx.x;
  const int wv = tid >> 6, ln = tid & 63;
  const int lane15 = ln & 15, quad = ln >> 4;
  const int bm = blockIdx.x * 128;
  f32x4 acc[8][4] = {};
  const int NS = K >> 5;

  auto stage_B = [&](int buf, int k0) {
#pragma unroll
    for (int q = 2; q < 6; ++q) {
      int L = q * 256 + tid;
      int rr = L >> 2, ck = (L & 3) * 8;
      glds16(Bt + (size_t)(rr - 128) * K + k0 + ck,
             sm[buf] + (size_t)(q * 256 + (tid & 192)) * 8);
    }
  };
  auto compute_tile = [&](const unsigned short* smc) {
    const unsigned short* Bsm = smc + 128 * 32;
    short8 af[8], bfr[4];
#pragma unroll
    for (int t = 0; t < 8; ++t)
      af[t] = *(const short8*)&smc[(t * 16 + lane15) * 32 + quad * 8];
#pragma unroll
    for (int t = 0; t < 4; ++t)
      bfr[t] = *(const short8*)&Bsm[(wv * 64 + t * 16 + lane15) * 32 + quad * 8];
#pragma unroll
    for (int mt = 0; mt < 8; ++mt)
#pragma unroll
      for (int nt = 0; nt < 4; ++nt)
        acc[mt][nt] = __builtin_amdgcn_mfma_f32_16x16x32_bf16(af[mt], bfr[nt],
                                                              acc[mt][nt], 0, 0, 0);
  };

  const int ar_ = tid >> 1, aks = (tid & 1) * 16;
  int agr = bm + ar_;
  if (agr > M - 1) agr = M - 1;
  const float* aRow = Af + (size_t)agr * K;

  auto convA = [&](int buf, float4 f0, float4 f1, float4 f2, float4 f3) {
    __attribute__((aligned(16))) unsigned int o[8];
    o[0] = cvt_pk(f0.x, f0.y); o[1] = cvt_pk(f0.z, f0.w);
    o[2] = cvt_pk(f1.x, f1.y); o[3] = cvt_pk(f1.z, f1.w);
    o[4] = cvt_pk(f2.x, f2.y); o[5] = cvt_pk(f2.z, f2.w);
    o[6] = cvt_pk(f3.x, f3.y); o[7] = cvt_pk(f3.z, f3.w);
    *(uint4*)&sm[buf][ar_ * 32 + aks] = *(uint4*)&o[0];
    *(uint4*)&sm[buf][ar_ * 32 + aks + 8] = *(uint4*)&o[4];
  };

  {
    const float* p = aRow + aks;
    float4 f0 = *(const float4*)(p), f1 = *(const float4*)(p + 4);
    float4 f2 = *(const float4*)(p + 8), f3 = *(const float4*)(p + 12);
    stage_B(0, 0);
    convA(0, f0, f1, f2, f3);
  }
  __syncthreads();

  int cur = 0;
  for (int s = 0; s < NS; ++s) {
    const int nb = cur ^ 1;
    const bool has_next = (s + 1 < NS);
    float4 nf0, nf1, nf2, nf3;
    if (has_next) {
      const float* p = aRow + (s + 1) * 32 + aks;
      nf0 = *(const float4*)(p);
      nf1 = *(const float4*)(p + 4);
      nf2 = *(const float4*)(p + 8);
      nf3 = *(const float4*)(p + 12);
      stage_B(nb, (s + 1) * 32);
    }
    compute_tile(sm[cur]);
    if (has_next) convA(nb, nf0, nf1, nf2, nf3);
    __syncthreads();
    cur = nb;
  }

  float bsum[4];
#pragma unroll
  for (int nt = 0; nt < 4; ++nt) bsum[nt] = bias1[wv * 64 + nt * 16 + lane15];
#pragma unroll
  for (int mt = 0; mt < 8; ++mt)
#pragma unroll
    for (int r = 0; r < 4; ++r) {
      int row = bm + mt * 16 + quad * 4 + r;
      if (row < M) {
#pragma unroll
        for (int nt = 0; nt < 4; ++nt)
          Cb[(size_t)row * 256 + wv * 64 + nt * 16 + lane15] =
              f2bf(fmaxf(acc[mt][nt][r] + bsum[nt], 0.f));
      }
    }
}

// ---------------- layer GEMM: BM=128, 8-wave blocks, 3-buf counted vmcnt ---
// (R10, unchanged — 16 waves/CU won)
template <int EPI>
__global__ __launch_bounds__(512, 4) void layer_mfma(
    const unsigned short* __restrict__ A, const unsigned short* __restrict__ Bt,
    const unsigned short* __restrict__ A2, const unsigned short* __restrict__ B2t,
    const float* __restrict__ bias1, const float* __restrict__ bias2,
    const float* __restrict__ gamma, const float* __restrict__ beta,
    unsigned short* __restrict__ Cb, float* __restrict__ Cf, int M) {
  __shared__ __attribute__((aligned(16))) unsigned short sm[3][384 * 32];  // 72KB
  __shared__ float red1[4][128], red2[4][128];
  __shared__ float mu_s[128], rs_s[128];
  const int tid = threadIdx.x;
  const int wv = tid >> 6, ln = tid & 63;
  const int lane15 = ln & 15, quad = ln >> 4;
  const int wr = wv >> 2, wc = wv & 3;  // 2M x 4N wave grid
  const int bm = blockIdx.x * 128;
  f32x4 acc[4][4] = {};

  auto stage = [&](int buf, int s) {
    const unsigned short* __restrict__ Ap = (s < 8) ? A : A2;
    const unsigned short* __restrict__ Bp = (s < 8) ? Bt : B2t;
    const int k0 = (s & 7) * 32;
#pragma unroll
    for (int q = 0; q < 3; ++q) {
      int L = q * 512 + tid;
      int r = L >> 2, ck = (L & 3) * 8;
      const unsigned short* gp;
      if (r < 128) {
        int gr = bm + r;
        if (gr > M - 1) gr = M - 1;
        gp = Ap + (size_t)gr * 256 + k0 + ck;
      } else {
        gp = Bp + (size_t)(r - 128) * 256 + k0 + ck;
      }
      glds16(gp, sm[buf] + (size_t)(q * 512 + (tid & 448)) * 8);
    }
  };
  auto compute_tile = [&](const unsigned short* smc) {
    const unsigned short* Bsm = smc + 128 * 32;
    short8 af[4], bfr[4];
#pragma unroll
    for (int t = 0; t < 4; ++t) {
      af[t] = *(const short8*)&smc[(wr * 64 + t * 16 + lane15) * 32 + quad * 8];
      bfr[t] = *(const short8*)&Bsm[(wc * 64 + t * 16 + lane15) * 32 + quad * 8];
    }
#pragma unroll
    for (int mt = 0; mt < 4; ++mt)
#pragma unroll
      for (int nt = 0; nt < 4; ++nt)
        acc[mt][nt] = __builtin_amdgcn_mfma_f32_16x16x32_bf16(af[mt], bfr[nt],
                                                              acc[mt][nt], 0, 0, 0);
  };

  stage(0, 0);
  stage(1, 1);
  for (int s = 0; s < 16; ++s) {
    if (s < 15) {
      asm volatile("s_waitcnt vmcnt(3)" ::: "memory");  // next tile stays in flight
    } else {
      asm volatile("s_waitcnt vmcnt(0)" ::: "memory");
    }
    __builtin_amdgcn_sched_barrier(0);
    __builtin_amdgcn_s_barrier();
    __builtin_amdgcn_sched_barrier(0);
    if (s + 2 < 16) stage((s + 2) % 3, s + 2);  // overwrites buffer of compute(s-1)
    compute_tile(sm[s % 3]);
  }
  __builtin_amdgcn_sched_barrier(0);

  // ---- epilogue (in-place on acc): relu -> LN (-> L2norm) ----
  float bsum[4], gg[4], bb[4];
#pragma unroll
  for (int nt = 0; nt < 4; ++nt) {
    int col = wc * 64 + nt * 16 + lane15;
    bsum[nt] = bias1[col] + bias2[col];
    gg[nt] = gamma[col];
    bb[nt] = beta[col];
  }
#pragma unroll
  for (int mt = 0; mt < 4; ++mt)
#pragma unroll
    for (int nt = 0; nt < 4; ++nt)
#pragma unroll
      for (int r = 0; r < 4; ++r)
        acc[mt][nt][r] = fmaxf(acc[mt][nt][r] + bsum[nt], 0.f);

  float s1[4][4], s2[4][4];
#pragma unroll
  for (int mt = 0; mt < 4; ++mt)
#pragma unroll
    for (int r = 0; r < 4; ++r) {
      float a = 0.f, b = 0.f;
#pragma unroll
      for (int nt = 0; nt < 4; ++nt) {
        a += acc[mt][nt][r];
        b += acc[mt][nt][r] * acc[mt][nt][r];
      }
      s1[mt][r] = a;
      s2[mt][r] = b;
    }
#pragma unroll
  for (int st = 1; st < 16; st <<= 1)
#pragma unroll
    for (int mt = 0; mt < 4; ++mt)
#pragma unroll
      for (int r = 0; r < 4; ++r) {
        s1[mt][r] += __shfl_xor(s1[mt][r], st, 64);
        s2[mt][r] += __shfl_xor(s2[mt][r], st, 64);
      }
  if (lane15 == 0) {
#pragma unroll
    for (int mt = 0; mt < 4; ++mt)
#pragma unroll
      for (int r = 0; r < 4; ++r) {
        int rowl = wr * 64 + mt * 16 + quad * 4 + r;
        red1[wc][rowl] = s1[mt][r];
        red2[wc][rowl] = s2[mt][r];
      }
  }
  __syncthreads();
  if (tid < 128) {
    float a = red1[0][tid] + red1[1][tid] + red1[2][tid] + red1[3][tid];
    float b = red2[0][tid] + red2[1][tid] + red2[2][tid] + red2[3][tid];
    float mu = a * (1.f / 256.f);
    float var = fmaxf(b * (1.f / 256.f) - mu * mu, 0.f);
    mu_s[tid] = mu;
    rs_s[tid] = rsqrtf(var + 1e-5f);
  }
  __syncthreads();
#pragma unroll
  for (int mt = 0; mt < 4; ++mt)
#pragma unroll
    for (int r = 0; r < 4; ++r) {
      int rowl = wr * 64 + mt * 16 + quad * 4 + r;
      float mu = mu_s[rowl], rstd = rs_s[rowl];
#pragma unroll
      for (int nt = 0; nt < 4; ++nt)
        acc[mt][nt][r] = (acc[mt][nt][r] - mu) * rstd * gg[nt] + bb[nt];
    }

  if (EPI == 1) {
#pragma unroll
    for (int mt = 0; mt < 4; ++mt)
#pragma unroll
      for (int r = 0; r < 4; ++r) {
        int row = bm + wr * 64 + mt * 16 + quad * 4 + r;
        if (row < M) {
#pragma unroll
          for (int nt = 0; nt < 4; ++nt)
            Cb[(size_t)row * 256 + wc * 64 + nt * 16 + lane15] =
                f2bf(acc[mt][nt][r]);
        }
      }
    return;
  }

  // EPI==2: L2 normalize; store f32 Cf and bf16 Cb
  __syncthreads();
#pragma unroll
  for (int mt = 0; mt < 4; ++mt)
#pragma unroll
    for (int r = 0; r < 4; ++r) {
      float b = 0.f;
#pragma unroll
      for (int nt = 0; nt < 4; ++nt) b += acc[mt][nt][r] * acc[mt][nt][r];
      s2[mt][r] = b;
    }
#pragma unroll
  for (int st = 1; st < 16; st <<= 1)
#pragma unroll
    for (int mt = 0; mt < 4; ++mt)
#pragma unroll
      for (int r = 0; r < 4; ++r) s2[mt][r] += __shfl_xor(s2[mt][r], st, 64);
  if (lane15 == 0) {
#pragma unroll
    for (int mt = 0; mt < 4; ++mt)
#pragma unroll
      for (int r = 0; r < 4; ++r)
        red1[wc][wr * 64 + mt * 16 + quad * 4 + r] = s2[mt][r];
  }
  __syncthreads();
  if (tid < 128) {
    float b = red1[0][tid] + red1[1][tid] + red1[2][tid] + red1[3][tid];
    mu_s[tid] = 1.f / fmaxf(sqrtf(b), 1e-12f);
  }
  __syncthreads();
#pragma unroll
  for (int mt = 0; mt < 4; ++mt)
#pragma unroll
    for (int r = 0; r < 4; ++r) {
      int rowl = wr * 64 + mt * 16 + quad * 4 + r;
      int row = bm + rowl;
      float inv = mu_s[rowl];
      if (row < M) {
#pragma unroll
        for (int nt = 0; nt < 4; ++nt) {
          float y = acc[mt][nt][r] * inv;
          size_t idx = (size_t)row * 256 + wc * 64 + nt * 16 + lane15;
          Cf[idx] = y;
          Cb[idx] = f2bf(y);
        }
      }
    }
}

// ---------------- feat GEMM: single-read dual A-tile (R10 version) ---------
__global__ __launch_bounds__(256) void feat_mfma_kernel(
    const unsigned short* __restrict__ Hb, const int* __restrict__ i_idx,
    const int* __restrict__ j_idx, const unsigned short* __restrict__ W1t,
    const float* __restrict__ b1, unsigned short* __restrict__ z1) {
  __shared__ __attribute__((aligned(16))) unsigned short Aabs[128 * 32];
  __shared__ __attribute__((aligned(16))) unsigned short Aprd[128 * 32];
  __shared__ __attribute__((aligned(16))) unsigned short Blo[128 * 32];
  __shared__ __attribute__((aligned(16))) unsigned short Bhi[128 * 32];
  __shared__ int ii[128], jj[128];
  const int tid = threadIdx.x;
  const int wv = tid >> 6, ln = tid & 63;
  const int lane15 = ln & 15, quad = ln >> 4;
  const int mhalf = wv >> 1, nhalf = wv & 1;
  const int bm = blockIdx.x * 128;
  if (tid < 128) {
    int p = bm + tid;
    if (p > PAIRS - 1) p = PAIRS - 1;
    ii[tid] = i_idx[p];
    jj[tid] = j_idx[p];
  }
  f32x4 acc[4][4] = {};
  const int ar = tid >> 1;
  const int ak = (tid & 1) * 16;

  for (int k0 = 0; k0 < 256; k0 += 32) {
    __syncthreads();
#pragma unroll
    for (int q = 0; q < 2; ++q) {
      int L = q * 256 + tid;
      int r = L >> 2, ck = (L & 3) * 8;
      glds16(W1t + (size_t)r * 512 + k0 + ck,
             Blo + (size_t)(q * 256 + (tid & 192)) * 8);
      glds16(W1t + (size_t)r * 512 + 256 + k0 + ck,
             Bhi + (size_t)(q * 256 + (tid & 192)) * 8);
    }
    {
      int kk = k0 + ak;
      const unsigned short* hi = Hb + (size_t)ii[ar] * 256 + kk;
      const unsigned short* hj = Hb + (size_t)jj[ar] * 256 + kk;
      union U { uint4 v; unsigned short s[8]; };
      U a0, a1, c0, c1;
      a0.v = *(const uint4*)(hi);
      a1.v = *(const uint4*)(hi + 8);
      c0.v = *(const uint4*)(hj);
      c1.v = *(const uint4*)(hj + 8);
      __attribute__((aligned(16))) unsigned short oabs[16], oprd[16];
#pragma unroll
      for (int e = 0; e < 8; ++e) {
        float x = bf2f(a0.s[e]), y = bf2f(c0.s[e]);
        oabs[e] = f2bf(fabsf(x - y));
        oprd[e] = f2bf(x * y);
      }
#pragma unroll
      for (int e = 0; e < 8; ++e) {
        float x = bf2f(a1.s[e]), y = bf2f(c1.s[e]);
        oabs[8 + e] = f2bf(fabsf(x - y));
        oprd[8 + e] = f2bf(x * y);
      }
      *(short8*)&Aabs[ar * 32 + ak] = *(short8*)&oabs[0];
      *(short8*)&Aabs[ar * 32 + ak + 8] = *(short8*)&oabs[8];
      *(short8*)&Aprd[ar * 32 + ak] = *(short8*)&oprd[0];
      *(short8*)&Aprd[ar * 32 + ak + 8] = *(short8*)&oprd[8];
    }
    __syncthreads();
    short8 aA[4], aP[4], bL[4], bH[4];
#pragma unroll
    for (int t = 0; t < 4; ++t) {
      int arow = (mhalf * 64 + t * 16 + lane15) * 32 + quad * 8;
      int brow = (nhalf * 64 + t * 16 + lane15) * 32 + quad * 8;
      aA[t] = *(const short8*)&Aabs[arow];
      aP[t] = *(const short8*)&Aprd[arow];
      bL[t] = *(const short8*)&Blo[brow];
      bH[t] = *(const short8*)&Bhi[brow];
    }
#pragma unroll
    for (int mt = 0; mt < 4; ++mt)
#pragma unroll
      for (int nt = 0; nt < 4; ++nt) {
        acc[mt][nt] = __builtin_amdgcn_mfma_f32_16x16x32_bf16(aA[mt], bL[nt],
                                                              acc[mt][nt], 0, 0, 0);
        acc[mt][nt] = __builtin_amdgcn_mfma_f32_16x16x32_bf16(aP[mt], bH[nt],
                                                              acc[mt][nt], 0, 0, 0);
      }
  }

  float bsum[4];
#pragma unroll
  for (int nt = 0; nt < 4; ++nt) bsum[nt] = b1[nhalf * 64 + nt * 16 + lane15];
#pragma unroll
  for (int mt = 0; mt < 4; ++mt) {
    int rb = bm + mhalf * 64 + mt * 16 + quad * 4;
#pragma unroll
    for (int r = 0; r < 4; ++r) {
      int p = rb + r;
      if (p < PAIRS) {
#pragma unroll
        for (int nt = 0; nt < 4; ++nt) {
          float v = fmaxf(acc[mt][nt][r] + bsum[nt], 0.f);
          z1[(size_t)p * 128 + nhalf * 64 + nt * 16 + lane15] = f2bf(v);
        }
      }
    }
  }
}

// ---------------- z2 GEMM with fused logits, double-buffered ---------------
__global__ __launch_bounds__(256) void gemm_logits_kernel(
    const unsigned short* __restrict__ z1, const unsigned short* __restrict__ W2t,
    const float* __restrict__ b2, const float* __restrict__ W3,
    const float* __restrict__ b3, float* __restrict__ out) {
  __shared__ __attribute__((aligned(16))) unsigned short As[2][128 * 32];
  __shared__ __attribute__((aligned(16))) unsigned short Bs[2][128 * 32];
  __shared__ float red[2][128];
  const int tid = threadIdx.x;
  const int wv = tid >> 6, ln = tid & 63;
  const int lane15 = ln & 15, quad = ln >> 4;
  const int mhalf = wv >> 1, nhalf = wv & 1;
  const int bm = blockIdx.x * 128;
  f32x4 acc[4][4] = {};

  auto stageL = [&](int buf, int k0) {
#pragma unroll
    for (int q = 0; q < 2; ++q) {
      int L = (q * 4 + wv) * 64 + ln;
      int r = L >> 2, ck = (L & 3) * 8;
      int gr = bm + r;
      if (gr > PAIRS - 1) gr = PAIRS - 1;
      glds16(z1 + (size_t)gr * 128 + k0 + ck, As[buf] + (size_t)(q * 4 + wv) * 512);
      glds16(W2t + (size_t)r * 128 + k0 + ck, Bs[buf] + (size_t)(q * 4 + wv) * 512);
    }
  };

  stageL(0, 0);
  __syncthreads();

  int cur = 0;
  for (int s = 0; s < 4; ++s) {
    const int nb = cur ^ 1;
    if (s < 3) stageL(nb, (s + 1) * 32);
    short8 af[4], bfr[4];
#pragma unroll
    for (int t = 0; t < 4; ++t) {
      af[t] = *(const short8*)&As[cur][(mhalf * 64 + t * 16 + lane15) * 32 + quad * 8];
      bfr[t] = *(const short8*)&Bs[cur][(nhalf * 64 + t * 16 + lane15) * 32 + quad * 8];
    }
#pragma unroll
    for (int mt = 0; mt < 4; ++mt)
#pragma unroll
      for (int nt = 0; nt < 4; ++nt)
        acc[mt][nt] = __builtin_amdgcn_mfma_f32_16x16x32_bf16(af[mt], bfr[nt],
                                                              acc[mt][nt], 0, 0, 0);
    __syncthreads();
    cur = nb;
  }

  float bsum[4], w3v[4];
#pragma unroll
  for (int nt = 0; nt < 4; ++nt) {
    int col = nhalf * 64 + nt * 16 + lane15;
    bsum[nt] = b2[col];
    w3v[nt] = W3[col];
  }
  float p[4][4];
#pragma unroll
  for (int mt = 0; mt < 4; ++mt)
#pragma unroll
    for (int r = 0; r < 4; ++r) {
      float s = 0.f;
#pragma unroll
      for (int nt = 0; nt < 4; ++nt)
        s += fmaxf(acc[mt][nt][r] + bsum[nt], 0.f) * w3v[nt];
      p[mt][r] = s;
    }
#pragma unroll
  for (int st = 1; st < 16; st <<= 1)
#pragma unroll
    for (int mt = 0; mt < 4; ++mt)
#pragma unroll
      for (int r = 0; r < 4; ++r) p[mt][r] += __shfl_xor(p[mt][r], st, 64);
  if (lane15 == 0) {
#pragma unroll
    for (int mt = 0; mt < 4; ++mt)
#pragma unroll
      for (int r = 0; r < 4; ++r)
        red[nhalf][mhalf * 64 + mt * 16 + quad * 4 + r] = p[mt][r];
  }
  __syncthreads();
  if (tid < 128) {
    int prow = bm + tid;
    if (prow < PAIRS) out[prow] = red[0][tid] + red[1][tid] + b3[0];
  }
}

// ---------------- graph aggregate ----------------

__global__ __launch_bounds__(256) void aggregate_kernel(
    const unsigned short* __restrict__ h, const int* __restrict__ row_start,
    const int* __restrict__ csr, const float* __restrict__ degf,
    unsigned short* __restrict__ mean) {
  int wid = threadIdx.x >> 6, lane = threadIdx.x & 63;
  int n = blockIdx.x * 4 + wid;
  if (n >= NODES) return;
  int rs = row_start[n], re = row_start[n + 1];
  float a0 = 0.f, a1 = 0.f, a2 = 0.f, a3 = 0.f;
  int e = rs;
  for (; e + 2 <= re; e += 2) {
    int s0 = csr[e], s1 = csr[e + 1];
    ushort4 v0 = *(const ushort4*)(h + (size_t)s0 * 256 + lane * 4);
    ushort4 v1 = *(const ushort4*)(h + (size_t)s1 * 256 + lane * 4);
    a0 += bf2f(v0.x) + bf2f(v1.x);
    a1 += bf2f(v0.y) + bf2f(v1.y);
    a2 += bf2f(v0.z) + bf2f(v1.z);
    a3 += bf2f(v0.w) + bf2f(v1.w);
  }
  if (e < re) {
    ushort4 v0 = *(const ushort4*)(h + (size_t)csr[e] * 256 + lane * 4);
    a0 += bf2f(v0.x); a1 += bf2f(v0.y); a2 += bf2f(v0.z); a3 += bf2f(v0.w);
  }
  float inv = 1.0f / degf[n];
  uint2 o;
  o.x = cvt_pk(a0 * inv, a1 * inv);
  o.y = cvt_pk(a2 * inv, a3 * inv);
  *(uint2*)(mean + (size_t)n * 256 + lane * 4) = o;
}

// ---------------- host ----------------

extern "C" void kernel_launch(void* const* d_in, const int* in_sizes, int n_in,
                              void* d_out, int out_size, void* d_ws, size_t ws_size,
                              hipStream_t stream) {
  const float* X       = (const float*)d_in[0];
  const int*   edge    = (const int*)d_in[1];
  const int*   i_idx   = (const int*)d_in[2];
  const int*   j_idx   = (const int*)d_in[3];
  const float* W_in    = (const float*)d_in[4];
  const float* b_in    = (const float*)d_in[5];
  const float* Ws_self = (const float*)d_in[6];
  const float* bs_self = (const float*)d_in[7];
  const float* Ws_nei  = (const float*)d_in[8];
  const float* bs_nei  = (const float*)d_in[9];
  const float* gammas  = (const float*)d_in[10];
  const float* betas   = (const float*)d_in[11];
  const float* W1      = (const float*)d_in[12];
  const float* b1      = (const float*)d_in[13];
  const float* W2      = (const float*)d_in[14];
  const float* b2      = (const float*)d_in[15];
  const float* W3      = (const float*)d_in[16];
  const float* b3      = (const float*)d_in[17];

  char* w = (char*)d_ws;
  size_t off = 0;
  auto alloc = [&](size_t bytes) {
    char* p = w + off;
    off += (bytes + 255) & ~(size_t)255;
    return p;
  };
  unsigned short* hA   = (unsigned short*)alloc((size_t)NODES * 256 * 2);  // 25.6MB
  unsigned short* hB   = (unsigned short*)alloc((size_t)NODES * 256 * 2);
  unsigned short* mean = (unsigned short*)alloc((size_t)NODES * 256 * 2);
  unsigned short* Hb   = (unsigned short*)alloc((size_t)NODES * 256 * 2);
  float* degf     = (float*)alloc((size_t)NODES * 4);
  int* cnt        = (int*)alloc((size_t)2 * NODES * 4);
  int* cursor     = cnt + NODES;
  int* row_start  = (int*)alloc((size_t)(NODES + 1) * 4);
  int* csr        = (int*)alloc((size_t)EDGES * 4);
  int* bsum       = (int*)alloc((size_t)(SCAN_BLK + 1) * 4);
  int* boff       = (int*)alloc((size_t)(SCAN_BLK + 1) * 4);
  unsigned short* WinT   = (unsigned short*)alloc((size_t)480 * 256 * 2);
  unsigned short* WselfT = (unsigned short*)alloc((size_t)3 * 256 * 256 * 2);
  unsigned short* WneiT  = (unsigned short*)alloc((size_t)3 * 256 * 256 * 2);
  unsigned short* W1T    = (unsigned short*)alloc((size_t)512 * 128 * 2);
  unsigned short* W2T    = (unsigned short*)alloc((size_t)128 * 128 * 2);
  unsigned short* z1 = hA;  // reuse (hA/hB dead after layer 3)

  const int* src = edge;
  const int* dst = edge + EDGES;
  float* Hout   = (float*)d_out;
  float* logits = (float*)d_out + (size_t)NODES * 256;

  // weight conversions
  tconv_kernel<<<dim3(8, 15, 1), 256, 0, stream>>>(W_in, WinT, 480, 256);
  tconv_kernel<<<dim3(8, 8, 3), 256, 0, stream>>>(Ws_self, WselfT, 256, 256);
  tconv_kernel<<<dim3(8, 8, 3), 256, 0, stream>>>(Ws_nei, WneiT, 256, 256);
  tconv_kernel<<<dim3(4, 16, 1), 256, 0, stream>>>(W1, W1T, 512, 128);
  tconv_kernel<<<dim3(4, 4, 1), 256, 0, stream>>>(W2, W2T, 128, 128);

  // CSR build (hierarchical scan)
  hipMemsetAsync(cnt, 0, (size_t)2 * NODES * 4, stream);
  count_deg_kernel<<<(EDGES + 255) / 256, 256, 0, stream>>>(dst, cnt);
  blocksum_kernel<<<SCAN_BLK, 256, 0, stream>>>(cnt, bsum);
  scan_bsum_kernel<<<1, 64, 0, stream>>>(bsum, boff);
  scan_final_kernel<<<SCAN_BLK, 256, 0, stream>>>(cnt, boff, row_start, degf);
  fill_csr_kernel<<<(EDGES + 255) / 256, 256, 0, stream>>>(src, dst, row_start, cursor, csr);

  // encoder: hA = relu(X @ W_in + b_in), fp32 A staged in-kernel, BM=128
  enc_mfma<<<391, 256, 0, stream>>>(X, WinT, b_in, hA, NODES, 480);

  unsigned short* hcur = hA;
  unsigned short* hnext = hB;
  for (int l = 0; l < 3; ++l) {
    aggregate_kernel<<<NODES / 4, 256, 0, stream>>>(hcur, row_start, csr, degf, mean);
    if (l < 2) {
      layer_mfma<1><<<391, 512, 0, stream>>>(
          hcur, WselfT + (size_t)l * 65536, mean, WneiT + (size_t)l * 65536,
          bs_self + l * 256, bs_nei + l * 256, gammas + l * 256, betas + l * 256,
          hnext, nullptr, NODES);
      unsigned short* t = hcur; hcur = hnext; hnext = t;
    } else {
      layer_mfma<2><<<391, 512, 0, stream>>>(
          hcur, WselfT + (size_t)l * 65536, mean, WneiT + (size_t)l * 65536,
          bs_self + l * 256, bs_nei + l * 256, gammas + l * 256, betas + l * 256,
          Hb, Hout, NODES);
    }
  }

  // edge head
  feat_mfma_kernel<<<(PAIRS + 127) / 128, 256, 0, stream>>>(Hb, i_idx, j_idx, W1T, b1, z1);
  gemm_logits_kernel<<<(PAIRS + 127) / 128, 256, 0, stream>>>(z1, W2T, b2, W3, b3, logits);
}